// Round 11
// baseline (352.270 us; speedup 1.0000x reference)
//
#include <hip/hip_runtime.h>
#include <hip/hip_bf16.h>
#include <hip/hip_fp16.h>

#define NN 100000
#define NG 256
#define NE 800000

constexpr int F0 = 114;   // x features
constexpr int F1 = 230;   // layer1 output features
constexpr int F2 = 115;   // layer2 output features
constexpr int MPAD = 100096;  // 1564 * 64

typedef _Float16 __attribute__((ext_vector_type(8))) f16x8;   // MFMA operand
typedef __attribute__((ext_vector_type(4))) float f32x4;      // MFMA acc
typedef __attribute__((ext_vector_type(8))) unsigned short u16x8;

__device__ __forceinline__ unsigned short f2h_bits(float x) {
  _Float16 h = (_Float16)x;
  return __builtin_bit_cast(unsigned short, h);
}
__device__ __forceinline__ float h_bits2f(unsigned short u) {
  return (float)__builtin_bit_cast(_Float16, u);
}

// ---------------- degree / CSR build ----------------

__global__ void k_count(const int* __restrict__ dst, int* __restrict__ cnt) {
  int e = blockIdx.x * blockDim.x + threadIdx.x;
  if (e < NE) atomicAdd(&cnt[dst[e]], 1);
}

__global__ void k_dinv(const int* __restrict__ cnt, float* __restrict__ dinv) {
  int i = blockIdx.x * blockDim.x + threadIdx.x;
  if (i < NN) dinv[i] = rsqrtf((float)cnt[i] + 1.0f);
}

constexpr int SCAN_T = 256;
constexpr int SCAN_E = 1024;
constexpr int NB = (NN + SCAN_E - 1) / SCAN_E;  // 98

__global__ void k_scan1(const int* __restrict__ cnt, int* __restrict__ off,
                        int* __restrict__ bsum) {
  __shared__ int s[SCAN_T];
  int b = blockIdx.x, t = threadIdx.x;
  int base = b * SCAN_E + t * 4;
  int v0 = 0, v1 = 0, v2 = 0, v3 = 0;
  if (base + 0 < NN) v0 = cnt[base + 0];
  if (base + 1 < NN) v1 = cnt[base + 1];
  if (base + 2 < NN) v2 = cnt[base + 2];
  if (base + 3 < NN) v3 = cnt[base + 3];
  int sum = v0 + v1 + v2 + v3;
  s[t] = sum;
  __syncthreads();
  for (int ofs = 1; ofs < SCAN_T; ofs <<= 1) {
    int x = (t >= ofs) ? s[t - ofs] : 0;
    __syncthreads();
    s[t] += x;
    __syncthreads();
  }
  int excl = s[t] - sum;
  if (base + 0 < NN) off[base + 0] = excl;
  if (base + 1 < NN) off[base + 1] = excl + v0;
  if (base + 2 < NN) off[base + 2] = excl + v0 + v1;
  if (base + 3 < NN) off[base + 3] = excl + v0 + v1 + v2;
  if (t == SCAN_T - 1) bsum[b] = s[t];
}

// wave-parallel exclusive scan of the 98 block sums (was serial pointer-chase)
__global__ void k_scan2(int* bsum) {
  __shared__ int ws[2];
  int t = threadIdx.x;  // 128
  int v = (t < NB) ? bsum[t] : 0;
  int orig = v;
  for (int o = 1; o < 64; o <<= 1) {
    int x = __shfl_up(v, o, 64);
    if ((t & 63) >= o) v += x;
  }
  if ((t & 63) == 63) ws[t >> 6] = v;
  __syncthreads();
  if (t >= 64) v += ws[0];
  if (t < NB) bsum[t] = v - orig;
}

__global__ void k_scan3(int* __restrict__ off, const int* __restrict__ bsum,
                        int* __restrict__ cur) {
  int i = blockIdx.x * blockDim.x + threadIdx.x;
  if (i < NN) {
    int v = off[i] + bsum[i / SCAN_E];
    off[i] = v;
    cur[i] = v;
  }
  if (i == NN) off[NN] = NE;
}

__global__ void k_place(const int* __restrict__ src, const int* __restrict__ dst,
                        int* __restrict__ cur, int* __restrict__ srcs) {
  int e = blockIdx.x * blockDim.x + threadIdx.x;
  if (e >= NE) return;
  int p = atomicAdd(&cur[dst[e]], 1);
  srcs[p] = src[e];
}

// ---------------- fp16 tables ----------------

__global__ void k_prepx(const float* __restrict__ x, const float* __restrict__ dinv,
                        unsigned short* __restrict__ xd) {
  int n = blockIdx.x, f = threadIdx.x;  // 128 threads
  float v = (f < F0) ? x[(size_t)n * F0 + f] * dinv[n] : 0.0f;
  xd[(size_t)n * 128 + f] = f2h_bits(v);
}

// ---------------- wave-per-node gather: 16 edge slots/iter, 4 loads in flight

template <bool POOL>
__global__ __launch_bounds__(256) void k_gatherw(
    const unsigned short* __restrict__ tab, const float* __restrict__ dinv,
    const int* __restrict__ off, const int* __restrict__ srcs,
    const float* __restrict__ b2, const int* __restrict__ batch,
    unsigned short* __restrict__ outh, float* __restrict__ pooled) {
  __shared__ float smax[4][128];
  __shared__ int sg[4];
  int w = threadIdx.x >> 6, lane = threadIdx.x & 63;
  int n = blockIdx.x * 4 + w;
  int grp = lane >> 4, sub = lane & 15;
  int fb = sub * 8;

  float acc[8] = {0.f, 0.f, 0.f, 0.f, 0.f, 0.f, 0.f, 0.f};
  int j0 = off[n], j1 = off[n + 1];  // slots j0..j1, self at j1
  for (int base = j0; base <= j1; base += 16) {
    int row[4];
    u16x8 v[4];
    bool has[4];
#pragma unroll
    for (int c = 0; c < 4; ++c) {
      int je = base + c * 4 + grp;
      row[c] = (je < j1) ? srcs[je] : ((je == j1) ? n : -1);
      has[c] = row[c] >= 0;
    }
#pragma unroll
    for (int c = 0; c < 4; ++c)
      if (has[c]) v[c] = *(const u16x8*)&tab[(size_t)row[c] * 128 + fb];
#pragma unroll
    for (int c = 0; c < 4; ++c)
      if (has[c]) {
#pragma unroll
        for (int u = 0; u < 8; ++u) acc[u] += h_bits2f(v[c][u]);
      }
  }
#pragma unroll
  for (int u = 0; u < 8; ++u) {
    acc[u] += __shfl_xor(acc[u], 16);
    acc[u] += __shfl_xor(acc[u], 32);
  }
  float dn = dinv[n];

  if constexpr (!POOL) {
    if (grp == 0) {
      u16x8 o;
#pragma unroll
      for (int u = 0; u < 8; ++u) o[u] = f2h_bits(acc[u] * dn);
      *(u16x8*)&outh[(size_t)n * 128 + fb] = o;
    }
  } else {
    if (grp == 0) {
#pragma unroll
      for (int u = 0; u < 8; ++u) {
        int f = fb + u;
        float bb = (f < F2) ? b2[f] : 0.0f;
        smax[w][f] = fmaxf(acc[u] * dn + bb, 0.0f);
      }
      if (sub == 0) sg[w] = batch[n];
    }
    __syncthreads();
    int t = threadIdx.x;
    if (t < 128) {
      int g0 = sg[0];
      bool same = (sg[1] == g0) & (sg[2] == g0) & (sg[3] == g0);
      if (same) {
        float m = fmaxf(fmaxf(smax[0][t], smax[1][t]),
                        fmaxf(smax[2][t], smax[3][t]));
        if (t < F2 && m > 0.0f)
          atomicMax((int*)&pooled[g0 * F2 + t], __float_as_int(m));
      } else {
        for (int ww = 0; ww < 4; ++ww) {
          float m = smax[ww][t];
          if (t < F2 && m > 0.0f)
            atomicMax((int*)&pooled[sg[ww] * F2 + t], __float_as_int(m));
        }
      }
    }
  }
}

// ---------------- weight split+transpose prep: Bt[n][k], fp16 hi/lo ----------------

__global__ void k_prepB(const float* __restrict__ W, unsigned short* __restrict__ Bh,
                        unsigned short* __restrict__ Bl, int K, int N, int KP) {
  int n = blockIdx.x, k = threadIdx.x;  // blockDim.x == KP
  float v = (k < K && n < N) ? W[(size_t)k * N + n] : 0.0f;
  unsigned short h = f2h_bits(v);
  unsigned short l = f2h_bits(v - h_bits2f(h));
  Bh[(size_t)n * KP + k] = h;
  Bl[(size_t)n * KP + k] = l;
}

// ---------------- fused double GEMM v2: td = (relu(aggX@W1t^T+b1) @ W2t^T)*dinv
// 64-row blocks. XOR-swizzled LDS (48 KB exactly -> 3 blocks/CU):
//   h1s [64][128] us (16.4 KB), Bs [2][128][64] us (32.8 KB), byte ^= (row&7)<<4.
// A-fragments direct from global (L2-resident), hoisted before B-prefetch so
// MFMA waits vmcnt(16) not 0. B chunks reg-prefetched one round ahead (T14).
// Interleaved schedule: per h-half {stage1 kc0,kc1 -> h1s; stage2 kc0,kc1}.

__global__ __launch_bounds__(256, 3) void k_fused(
    const unsigned short* __restrict__ A,                                   // [MPAD][128]
    const unsigned short* __restrict__ B1h, const unsigned short* __restrict__ B1l,  // [256][128]
    const unsigned short* __restrict__ B2h, const unsigned short* __restrict__ B2l,  // [128][256]
    const float* __restrict__ b1, const float* __restrict__ dscale,
    unsigned short* __restrict__ td) {                                      // [MPAD][128]
  __shared__ char lds[49152];
  char* h1B = lds;            // 16384 B: 64 rows x 256 B
  char* Bs0 = lds + 16384;    // 16384 B: 128 rows x 128 B (hi)
  char* Bs1 = lds + 32768;    // (lo)

  const int t = threadIdx.x;
  const int m0 = blockIdx.x * 64;
  const int lane = t & 63, w = t >> 6;
  const int r = lane & 15;
  const int kq = lane >> 4;         // k-quarter 0..3
  const int kb2 = kq * 16;          // byte offset of k-fragment
  const int kbu = kq * 8;           // ushort offset
  const int rq = kq * 4;
  const int wc = w * 32;            // wave's 32-col slice
  const int brow = t >> 1, bseg = t & 1;
  const int rb = brow * 128, swb = (brow & 7) << 4;

  const unsigned short* Ath = A + (size_t)(m0 + r) * 128 + kbu;

  u16x8 Ph[4], Pl[4];
  f16x8 a[4][2];  // stage-1 A frags [i][ks], loaded per round
  f32x4 acc[4][2], acc2[4][2];
#pragma unroll
  for (int i = 0; i < 4; ++i)
#pragma unroll
    for (int j = 0; j < 2; ++j) {
      acc[i][j] = (f32x4){0.f, 0.f, 0.f, 0.f};
      acc2[i][j] = (f32x4){0.f, 0.f, 0.f, 0.f};
    }

  auto issueB = [&](const unsigned short* Gh, const unsigned short* Gl, size_t base) {
#pragma unroll
    for (int v = 0; v < 4; ++v) {
      Ph[v] = *(const u16x8*)&Gh[base + v * 8];
      Pl[v] = *(const u16x8*)&Gl[base + v * 8];
    }
  };
  auto commitB = [&]() {
#pragma unroll
    for (int v = 0; v < 4; ++v) {
      const int bo = (bseg * 64 + v * 16) ^ swb;
      *(u16x8*)(Bs0 + rb + bo) = Ph[v];
      *(u16x8*)(Bs1 + rb + bo) = Pl[v];
    }
  };
  auto loadA = [&](int kc) {
#pragma unroll
    for (int i = 0; i < 4; ++i)
#pragma unroll
      for (int ks = 0; ks < 2; ++ks)
        a[i][ks] = *(const f16x8*)&Ath[i * 2048 + kc * 64 + ks * 32];
  };
  auto mfma1 = [&]() {
#pragma unroll
    for (int ks = 0; ks < 2; ++ks) {
      f16x8 bh[2], bl[2];
#pragma unroll
      for (int j = 0; j < 2; ++j) {
        const int row = wc + j * 16 + r;
        const int bo = (ks * 64 + kb2) ^ ((row & 7) << 4);
        bh[j] = *(const f16x8*)(Bs0 + row * 128 + bo);
        bl[j] = *(const f16x8*)(Bs1 + row * 128 + bo);
      }
#pragma unroll
      for (int i = 0; i < 4; ++i)
#pragma unroll
        for (int j = 0; j < 2; ++j)
          acc[i][j] = __builtin_amdgcn_mfma_f32_16x16x32_f16(a[i][ks], bl[j], acc[i][j], 0, 0, 0);
#pragma unroll
      for (int i = 0; i < 4; ++i)
#pragma unroll
        for (int j = 0; j < 2; ++j)
          acc[i][j] = __builtin_amdgcn_mfma_f32_16x16x32_f16(a[i][ks], bh[j], acc[i][j], 0, 0, 0);
    }
  };
  auto mfma2 = [&](int kc) {
#pragma unroll
    for (int ks = 0; ks < 2; ++ks) {
      f16x8 ah[4], bh[2], bl[2];
#pragma unroll
      for (int i = 0; i < 4; ++i) {
        const int row = i * 16 + r;
        ah[i] = *(const f16x8*)(h1B + row * 256 +
                                ((kc * 128 + ks * 64 + kb2) ^ ((row & 7) << 4)));
      }
#pragma unroll
      for (int j = 0; j < 2; ++j) {
        const int row = wc + j * 16 + r;
        const int bo = (ks * 64 + kb2) ^ ((row & 7) << 4);
        bh[j] = *(const f16x8*)(Bs0 + row * 128 + bo);
        bl[j] = *(const f16x8*)(Bs1 + row * 128 + bo);
      }
#pragma unroll
      for (int i = 0; i < 4; ++i)
#pragma unroll
        for (int j = 0; j < 2; ++j)
          acc2[i][j] = __builtin_amdgcn_mfma_f32_16x16x32_f16(ah[i], bl[j], acc2[i][j], 0, 0, 0);
#pragma unroll
      for (int i = 0; i < 4; ++i)
#pragma unroll
        for (int j = 0; j < 2; ++j)
          acc2[i][j] = __builtin_amdgcn_mfma_f32_16x16x32_f16(ah[i], bh[j], acc2[i][j], 0, 0, 0);
    }
  };
  auto writeH1 = [&](int h) {
    // C/D layout: col = lane&15 (n), row = kq*4 + q (m)  [m89/m91]
#pragma unroll
    for (int i = 0; i < 4; ++i)
#pragma unroll
      for (int j = 0; j < 2; ++j) {
        const int nl = wc + j * 16 + r;
        const int n = h * 128 + nl;
        const bool val = n < F1;
        const float bb = val ? b1[n] : 0.0f;
#pragma unroll
        for (int q = 0; q < 4; ++q) {
          const int ml = i * 16 + rq + q;
          const float v = val ? fmaxf(acc[i][j][q] + bb, 0.0f) : 0.0f;
          *(unsigned short*)(h1B + ml * 256 + ((nl * 2) ^ ((ml & 7) << 4))) = f2h_bits(v);
        }
      }
  };
  auto zacc = [&]() {
#pragma unroll
    for (int i = 0; i < 4; ++i)
#pragma unroll
      for (int j = 0; j < 2; ++j) acc[i][j] = (f32x4){0.f, 0.f, 0.f, 0.f};
  };
  auto B1BASE = [&](int h, int kc) {
    return (size_t)(h * 128 + brow) * 128 + kc * 64 + bseg * 32;
  };
  auto B2BASE = [&](int h, int kc) {
    return (size_t)brow * 256 + h * 128 + kc * 64 + bseg * 32;
  };

  // prologue
  issueB(B1h, B1l, B1BASE(0, 0));

  // R0: stage1 h0 kc0
  commitB(); loadA(0); issueB(B1h, B1l, B1BASE(0, 1));
  __syncthreads(); mfma1();
  // R1: stage1 h0 kc1
  __syncthreads(); commitB(); loadA(1); issueB(B2h, B2l, B2BASE(0, 0));
  __syncthreads(); mfma1(); writeH1(0);
  // R2: stage2 h0 kc0   (sync fences h1s writes)
  __syncthreads(); commitB(); issueB(B2h, B2l, B2BASE(0, 1));
  __syncthreads(); mfma2(0);
  // R3: stage2 h0 kc1
  __syncthreads(); commitB(); issueB(B1h, B1l, B1BASE(1, 0));
  __syncthreads(); mfma2(1);
  // R4: stage1 h1 kc0
  zacc();
  __syncthreads(); commitB(); loadA(0); issueB(B1h, B1l, B1BASE(1, 1));
  __syncthreads(); mfma1();
  // R5: stage1 h1 kc1
  __syncthreads(); commitB(); loadA(1); issueB(B2h, B2l, B2BASE(1, 0));
  __syncthreads(); mfma1(); writeH1(1);
  // R6: stage2 h1 kc0
  __syncthreads(); commitB(); issueB(B2h, B2l, B2BASE(1, 1));
  __syncthreads(); mfma2(0);
  // R7: stage2 h1 kc1
  __syncthreads(); commitB();
  __syncthreads(); mfma2(1);

  // epilogue: scale, stage fp16 tile into h1B (swizzled), coalesced store
  __syncthreads();
#pragma unroll
  for (int i = 0; i < 4; ++i)
#pragma unroll
    for (int j = 0; j < 2; ++j) {
      const int nl = wc + j * 16 + r;
#pragma unroll
      for (int q = 0; q < 4; ++q) {
        const int ml = i * 16 + rq + q;
        const float v = acc2[i][j][q] * dscale[m0 + ml];
        *(unsigned short*)(h1B + ml * 256 + ((nl * 2) ^ ((ml & 7) << 4))) = f2h_bits(v);
      }
    }
  __syncthreads();
  {
    const int row = t >> 2, seg = t & 3;
    const int swz = (row & 7) << 4;
    const size_t dst = (size_t)(m0 + row) * 128 + seg * 32;
#pragma unroll
    for (int v = 0; v < 4; ++v) {
      u16x8 d = *(const u16x8*)(h1B + row * 256 + ((seg * 64 + v * 16) ^ swz));
      *(u16x8*)&td[dst + v * 8] = d;
    }
  }
}

// ---------------- tiny MLP head: 115 -> 64 -> 32 -> 1 ----------------

__global__ void k_mlp(const float* __restrict__ pooled,
                      const float* __restrict__ Wg, const float* __restrict__ bg,
                      const float* __restrict__ Wf, const float* __restrict__ bf,
                      const float* __restrict__ Wo, const float* __restrict__ bo,
                      float* __restrict__ out) {
  __shared__ float sp[F2];
  __shared__ float sg[64];
  __shared__ float sf[32];
  int g = blockIdx.x, t = threadIdx.x;
  for (int f = t; f < F2; f += 64) sp[f] = pooled[g * F2 + f];
  __syncthreads();
  float a = bg[t];
  for (int k = 0; k < F2; ++k) a += sp[k] * Wg[k * 64 + t];
  sg[t] = fmaxf(a, 0.0f);
  __syncthreads();
  if (t < 32) {
    float c = bf[t];
    for (int k = 0; k < 64; ++k) c += sg[k] * Wf[k * 32 + t];
    sf[t] = fmaxf(c, 0.0f);
  }
  __syncthreads();
  if (t == 0) {
    float c = bo[0];
    for (int k = 0; k < 32; ++k) c += sf[k] * Wo[k];
    out[g] = c;
  }
}

// ---------------- launch ----------------

extern "C" void kernel_launch(void* const* d_in, const int* in_sizes, int n_in,
                              void* d_out, int out_size, void* d_ws, size_t ws_size,
                              hipStream_t stream) {
  const float* x  = (const float*)d_in[0];
  const int* ei   = (const int*)d_in[1];
  const int* batch = (const int*)d_in[2];
  const float* W1 = (const float*)d_in[3];
  const float* b1 = (const float*)d_in[4];
  const float* W2 = (const float*)d_in[5];
  const float* b2 = (const float*)d_in[6];
  const float* Wg = (const float*)d_in[7];
  const float* bg = (const float*)d_in[8];
  const float* Wf = (const float*)d_in[9];
  const float* bf = (const float*)d_in[10];
  const float* Wo = (const float*)d_in[11];
  const float* bo = (const float*)d_in[12];
  const int* src = ei;
  const int* dst = ei + NE;

  char* p = (char*)d_ws;
  auto alloc4 = [&](size_t units) { void* r = p; p += units * 4; return r; };
  float* dinv  = (float*)alloc4(100224);
  int* cnt     = (int*)alloc4(100224);
  int* off     = (int*)alloc4(100352);
  int* cur     = (int*)alloc4(100224);
  int* bsum    = (int*)alloc4(128);
  int* srcs    = (int*)alloc4(NE);
  unsigned short* xd   = (unsigned short*)alloc4((size_t)NN * 128 / 2);    // 25.6MB
  unsigned short* aggX = (unsigned short*)alloc4((size_t)MPAD * 128 / 2);  // 25.6MB
  unsigned short* td   = (unsigned short*)alloc4((size_t)MPAD * 128 / 2);  // 25.6MB
  unsigned short* Bt1h = (unsigned short*)alloc4(256 * 128 / 2);
  unsigned short* Bt1l = (unsigned short*)alloc4(256 * 128 / 2);
  unsigned short* Bt2h = (unsigned short*)alloc4(128 * 256 / 2);
  unsigned short* Bt2l = (unsigned short*)alloc4(128 * 256 / 2);
  float* pooled = (float*)alloc4((size_t)NG * F2);

  hipMemsetAsync(cnt, 0, 100224 * sizeof(int), stream);
  hipMemsetAsync(pooled, 0, (size_t)NG * F2 * sizeof(float), stream);

  // CSR build (shared by both conv layers)
  k_count<<<(NE + 255) / 256, 256, 0, stream>>>(dst, cnt);
  k_dinv<<<(NN + 255) / 256, 256, 0, stream>>>(cnt, dinv);
  k_scan1<<<NB, SCAN_T, 0, stream>>>(cnt, off, bsum);
  k_scan2<<<1, 128, 0, stream>>>(bsum);
  k_scan3<<<(NN + 256) / 256, 256, 0, stream>>>(off, bsum, cur);
  k_place<<<(NE + 255) / 256, 256, 0, stream>>>(src, dst, cur, srcs);

  // weight prep (fp16 hi/lo, transposed, zero-padded)
  k_prepB<<<256, 128, 0, stream>>>(W1, Bt1h, Bt1l, F0, F1, 128);
  k_prepB<<<128, 256, 0, stream>>>(W2, Bt2h, Bt2l, F1, F2, 256);

  // layer 1 input: fp16 table + wave-per-node gather -> aggX fp16
  k_prepx<<<NN, 128, 0, stream>>>(x, dinv, xd);
  k_gatherw<false><<<NN / 4, 256, 0, stream>>>(xd, dinv, off, srcs,
                                               nullptr, nullptr, aggX, nullptr);

  // fused conv1-GEMM + conv2-GEMM (h1 never leaves LDS) -> td fp16
  k_fused<<<MPAD / 64, 256, 0, stream>>>(aggX, Bt1h, Bt1l, Bt2h, Bt2l,
                                         b1, dinv, td);

  // layer 2 aggregation fused with relu(+b2) + per-graph max pool
  k_gatherw<true><<<NN / 4, 256, 0, stream>>>(td, dinv, off, srcs,
                                              b2, batch, nullptr, pooled);

  // head MLP
  k_mlp<<<NG, 64, 0, stream>>>(pooled, Wg, bg, Wf, bf, Wo, bo, (float*)d_out);
}

// Round 12
// 337.209 us; speedup vs baseline: 1.0447x; 1.0447x over previous
//
#include <hip/hip_runtime.h>
#include <hip/hip_bf16.h>
#include <hip/hip_fp16.h>

#define NN 100000
#define NG 256
#define NE 800000

constexpr int F0 = 114;   // x features
constexpr int F1 = 230;   // layer1 output features
constexpr int F2 = 115;   // layer2 output features
constexpr int MPAD = 100096;  // 1564 * 64

typedef _Float16 __attribute__((ext_vector_type(8))) f16x8;   // MFMA operand
typedef __attribute__((ext_vector_type(4))) float f32x4;      // MFMA acc
typedef __attribute__((ext_vector_type(8))) unsigned short u16x8;

__device__ __forceinline__ unsigned short f2h_bits(float x) {
  _Float16 h = (_Float16)x;
  return __builtin_bit_cast(unsigned short, h);
}
__device__ __forceinline__ float h_bits2f(unsigned short u) {
  return (float)__builtin_bit_cast(_Float16, u);
}

// ---------------- degree / CSR build ----------------

__global__ void k_count(const int* __restrict__ dst, int* __restrict__ cnt) {
  int e = blockIdx.x * blockDim.x + threadIdx.x;
  if (e < NE) atomicAdd(&cnt[dst[e]], 1);
}

__global__ void k_dinv(const int* __restrict__ cnt, float* __restrict__ dinv) {
  int i = blockIdx.x * blockDim.x + threadIdx.x;
  if (i < NN) dinv[i] = rsqrtf((float)cnt[i] + 1.0f);
}

constexpr int SCAN_T = 256;
constexpr int SCAN_E = 1024;
constexpr int NB = (NN + SCAN_E - 1) / SCAN_E;  // 98

__global__ void k_scan1(const int* __restrict__ cnt, int* __restrict__ off,
                        int* __restrict__ bsum) {
  __shared__ int s[SCAN_T];
  int b = blockIdx.x, t = threadIdx.x;
  int base = b * SCAN_E + t * 4;
  int v0 = 0, v1 = 0, v2 = 0, v3 = 0;
  if (base + 0 < NN) v0 = cnt[base + 0];
  if (base + 1 < NN) v1 = cnt[base + 1];
  if (base + 2 < NN) v2 = cnt[base + 2];
  if (base + 3 < NN) v3 = cnt[base + 3];
  int sum = v0 + v1 + v2 + v3;
  s[t] = sum;
  __syncthreads();
  for (int ofs = 1; ofs < SCAN_T; ofs <<= 1) {
    int x = (t >= ofs) ? s[t - ofs] : 0;
    __syncthreads();
    s[t] += x;
    __syncthreads();
  }
  int excl = s[t] - sum;
  if (base + 0 < NN) off[base + 0] = excl;
  if (base + 1 < NN) off[base + 1] = excl + v0;
  if (base + 2 < NN) off[base + 2] = excl + v0 + v1;
  if (base + 3 < NN) off[base + 3] = excl + v0 + v1 + v2;
  if (t == SCAN_T - 1) bsum[b] = s[t];
}

// wave-parallel exclusive scan of the 98 block sums
__global__ void k_scan2(int* bsum) {
  __shared__ int ws[2];
  int t = threadIdx.x;  // 128
  int v = (t < NB) ? bsum[t] : 0;
  int orig = v;
  for (int o = 1; o < 64; o <<= 1) {
    int x = __shfl_up(v, o, 64);
    if ((t & 63) >= o) v += x;
  }
  if ((t & 63) == 63) ws[t >> 6] = v;
  __syncthreads();
  if (t >= 64) v += ws[0];
  if (t < NB) bsum[t] = v - orig;
}

__global__ void k_scan3(int* __restrict__ off, const int* __restrict__ bsum,
                        int* __restrict__ cur) {
  int i = blockIdx.x * blockDim.x + threadIdx.x;
  if (i < NN) {
    int v = off[i] + bsum[i / SCAN_E];
    off[i] = v;
    cur[i] = v;
  }
  if (i == NN) off[NN] = NE;
}

__global__ void k_place(const int* __restrict__ src, const int* __restrict__ dst,
                        int* __restrict__ cur, int* __restrict__ srcs) {
  int e = blockIdx.x * blockDim.x + threadIdx.x;
  if (e >= NE) return;
  int p = atomicAdd(&cur[dst[e]], 1);
  srcs[p] = src[e];
}

// ---------------- fp16 tables ----------------

__global__ void k_prepx(const float* __restrict__ x, const float* __restrict__ dinv,
                        unsigned short* __restrict__ xd) {
  int n = blockIdx.x, f = threadIdx.x;  // 128 threads
  float v = (f < F0) ? x[(size_t)n * F0 + f] * dinv[n] : 0.0f;
  xd[(size_t)n * 128 + f] = f2h_bits(v);
}

// ---------------- wave-per-node gather: 16 edge slots/iter, 4 loads in flight

template <bool POOL>
__global__ __launch_bounds__(256) void k_gatherw(
    const unsigned short* __restrict__ tab, const float* __restrict__ dinv,
    const int* __restrict__ off, const int* __restrict__ srcs,
    const float* __restrict__ b2, const int* __restrict__ batch,
    unsigned short* __restrict__ outh, float* __restrict__ pooled) {
  __shared__ float smax[4][128];
  __shared__ int sg[4];
  int w = threadIdx.x >> 6, lane = threadIdx.x & 63;
  int n = blockIdx.x * 4 + w;
  int grp = lane >> 4, sub = lane & 15;
  int fb = sub * 8;

  float acc[8] = {0.f, 0.f, 0.f, 0.f, 0.f, 0.f, 0.f, 0.f};
  int j0 = off[n], j1 = off[n + 1];  // slots j0..j1, self at j1
  for (int base = j0; base <= j1; base += 16) {
    int row[4];
    u16x8 v[4];
    bool has[4];
#pragma unroll
    for (int c = 0; c < 4; ++c) {
      int je = base + c * 4 + grp;
      row[c] = (je < j1) ? srcs[je] : ((je == j1) ? n : -1);
      has[c] = row[c] >= 0;
    }
#pragma unroll
    for (int c = 0; c < 4; ++c)
      if (has[c]) v[c] = *(const u16x8*)&tab[(size_t)row[c] * 128 + fb];
#pragma unroll
    for (int c = 0; c < 4; ++c)
      if (has[c]) {
#pragma unroll
        for (int u = 0; u < 8; ++u) acc[u] += h_bits2f(v[c][u]);
      }
  }
#pragma unroll
  for (int u = 0; u < 8; ++u) {
    acc[u] += __shfl_xor(acc[u], 16);
    acc[u] += __shfl_xor(acc[u], 32);
  }
  float dn = dinv[n];

  if constexpr (!POOL) {
    if (grp == 0) {
      u16x8 o;
#pragma unroll
      for (int u = 0; u < 8; ++u) o[u] = f2h_bits(acc[u] * dn);
      *(u16x8*)&outh[(size_t)n * 128 + fb] = o;
    }
  } else {
    if (grp == 0) {
#pragma unroll
      for (int u = 0; u < 8; ++u) {
        int f = fb + u;
        float bb = (f < F2) ? b2[f] : 0.0f;
        smax[w][f] = fmaxf(acc[u] * dn + bb, 0.0f);
      }
      if (sub == 0) sg[w] = batch[n];
    }
    __syncthreads();
    int t = threadIdx.x;
    if (t < 128) {
      int g0 = sg[0];
      bool same = (sg[1] == g0) & (sg[2] == g0) & (sg[3] == g0);
      if (same) {
        float m = fmaxf(fmaxf(smax[0][t], smax[1][t]),
                        fmaxf(smax[2][t], smax[3][t]));
        if (t < F2 && m > 0.0f)
          atomicMax((int*)&pooled[g0 * F2 + t], __float_as_int(m));
      } else {
        for (int ww = 0; ww < 4; ++ww) {
          float m = smax[ww][t];
          if (t < F2 && m > 0.0f)
            atomicMax((int*)&pooled[sg[ww] * F2 + t], __float_as_int(m));
        }
      }
    }
  }
}

// ---------------- weight split+transpose prep: Bt[n][k], fp16 hi/lo ----------------

__global__ void k_prepB(const float* __restrict__ W, unsigned short* __restrict__ Bh,
                        unsigned short* __restrict__ Bl, int K, int N, int KP) {
  int n = blockIdx.x, k = threadIdx.x;  // blockDim.x == KP
  float v = (k < K && n < N) ? W[(size_t)k * N + n] : 0.0f;
  unsigned short h = f2h_bits(v);
  unsigned short l = f2h_bits(v - h_bits2f(h));
  Bh[(size_t)n * KP + k] = h;
  Bl[(size_t)n * KP + k] = l;
}

// ---------------- fused double GEMM v3: td = (relu(aggX@W1t^T+b1) @ W2t^T)*dinv
// Round-10 staging discipline (global->LDS in one phase, nothing held across
// barriers) + compact XOR-swizzled LDS (49.2 KB -> 3 blocks/CU) + A-fragments
// direct from L2-resident global inside the MFMA phase.
// Swizzle: byte ^= (row&7)<<4 within each 128B row-half.

__global__ __launch_bounds__(256, 3) void k_fused(
    const unsigned short* __restrict__ A,                                   // [MPAD][128]
    const unsigned short* __restrict__ B1h, const unsigned short* __restrict__ B1l,  // [256][128]
    const unsigned short* __restrict__ B2h, const unsigned short* __restrict__ B2l,  // [128][256]
    const float* __restrict__ b1, const float* __restrict__ dscale,
    unsigned short* __restrict__ td) {                                      // [MPAD][128]
  __shared__ char lds[49152];
  char* h1B = lds;            // 16384 B: 64 rows x 256 B (one 128-col half of h1)
  char* Bs0 = lds + 16384;    // 16384 B: 128 rows x 128 B (hi)
  char* Bs1 = lds + 32768;    // (lo)

  const int t = threadIdx.x;
  const int m0 = blockIdx.x * 64;
  const int lane = t & 63, w = t >> 6;
  const int r = lane & 15;
  const int kq = lane >> 4;         // k-quarter 0..3
  const int kb2 = kq * 16;          // byte offset of k-fragment
  const int kbu = kq * 8;           // ushort offset
  const int rq = kq * 4;
  const int wc = w * 32;            // wave's 32-col slice
  const int brow = t >> 1, bseg = t & 1;
  const int rb = brow * 128, swb = (brow & 7) << 4;

  const unsigned short* Ath = A + (size_t)(m0 + r) * 128 + kbu;

  f32x4 acc2[4][2];
#pragma unroll
  for (int i = 0; i < 4; ++i)
#pragma unroll
    for (int j = 0; j < 2; ++j) acc2[i][j] = (f32x4){0.f, 0.f, 0.f, 0.f};

  for (int h = 0; h < 2; ++h) {
    f32x4 acc[4][2];
#pragma unroll
    for (int i = 0; i < 4; ++i)
#pragma unroll
      for (int j = 0; j < 2; ++j) acc[i][j] = (f32x4){0.f, 0.f, 0.f, 0.f};

    // ---- stage 1 (this half): acc += aggX[:,kc*64..] @ B1[h*128.., kc*64..]
    for (int kc = 0; kc < 2; ++kc) {
      __syncthreads();  // Bs free (prev consumers done)
      {
        size_t gb = (size_t)(h * 128 + brow) * 128 + kc * 64 + bseg * 32;
#pragma unroll
        for (int v = 0; v < 4; ++v) {
          const int bo = rb + ((bseg * 64 + v * 16) ^ swb);
          *(u16x8*)(Bs0 + bo) = *(const u16x8*)&B1h[gb + v * 8];
          *(u16x8*)(Bs1 + bo) = *(const u16x8*)&B1l[gb + v * 8];
        }
      }
      __syncthreads();
#pragma unroll
      for (int ks = 0; ks < 2; ++ks) {
        f16x8 av[4], bh[2], bl[2];
#pragma unroll
        for (int i = 0; i < 4; ++i)
          av[i] = *(const f16x8*)&Ath[i * 2048 + kc * 64 + ks * 32];
#pragma unroll
        for (int j = 0; j < 2; ++j) {
          const int row = wc + j * 16 + r;
          const int bo = (ks * 64 + kb2) ^ ((row & 7) << 4);
          bh[j] = *(const f16x8*)(Bs0 + row * 128 + bo);
          bl[j] = *(const f16x8*)(Bs1 + row * 128 + bo);
        }
#pragma unroll
        for (int i = 0; i < 4; ++i)
#pragma unroll
          for (int j = 0; j < 2; ++j)
            acc[i][j] = __builtin_amdgcn_mfma_f32_16x16x32_f16(av[i], bl[j], acc[i][j], 0, 0, 0);
#pragma unroll
        for (int i = 0; i < 4; ++i)
#pragma unroll
          for (int j = 0; j < 2; ++j)
            acc[i][j] = __builtin_amdgcn_mfma_f32_16x16x32_f16(av[i], bh[j], acc[i][j], 0, 0, 0);
      }
    }

    // bias+relu -> h1B (swizzled); fenced by next round's barrier
    // C/D layout: col = lane&15 (n), row = kq*4 + q (m)  [m89/m91]
#pragma unroll
    for (int i = 0; i < 4; ++i)
#pragma unroll
      for (int j = 0; j < 2; ++j) {
        const int nl = wc + j * 16 + r;
        const int n = h * 128 + nl;
        const bool val = n < F1;
        const float bb = val ? b1[n] : 0.0f;
#pragma unroll
        for (int q = 0; q < 4; ++q) {
          const int ml = i * 16 + rq + q;
          const float v = val ? fmaxf(acc[i][j][q] + bb, 0.0f) : 0.0f;
          *(unsigned short*)(h1B + ml * 256 + ((nl * 2) ^ ((ml & 7) << 4))) = f2h_bits(v);
        }
      }

    // ---- stage 2 partial-K (this half): acc2 += h1B @ B2[:, h*128..]
    for (int kc = 0; kc < 2; ++kc) {
      __syncthreads();  // fences h1B writes (kc=0) and Bs reuse
      {
        size_t gb = (size_t)brow * 256 + h * 128 + kc * 64 + bseg * 32;
#pragma unroll
        for (int v = 0; v < 4; ++v) {
          const int bo = rb + ((bseg * 64 + v * 16) ^ swb);
          *(u16x8*)(Bs0 + bo) = *(const u16x8*)&B2h[gb + v * 8];
          *(u16x8*)(Bs1 + bo) = *(const u16x8*)&B2l[gb + v * 8];
        }
      }
      __syncthreads();
#pragma unroll
      for (int ks = 0; ks < 2; ++ks) {
        f16x8 ah[4], bh[2], bl[2];
#pragma unroll
        for (int i = 0; i < 4; ++i) {
          const int row = i * 16 + r;
          ah[i] = *(const f16x8*)(h1B + row * 256 +
                                  ((kc * 128 + ks * 64 + kb2) ^ ((row & 7) << 4)));
        }
#pragma unroll
        for (int j = 0; j < 2; ++j) {
          const int row = wc + j * 16 + r;
          const int bo = (ks * 64 + kb2) ^ ((row & 7) << 4);
          bh[j] = *(const f16x8*)(Bs0 + row * 128 + bo);
          bl[j] = *(const f16x8*)(Bs1 + row * 128 + bo);
        }
#pragma unroll
        for (int i = 0; i < 4; ++i)
#pragma unroll
          for (int j = 0; j < 2; ++j)
            acc2[i][j] = __builtin_amdgcn_mfma_f32_16x16x32_f16(ah[i], bl[j], acc2[i][j], 0, 0, 0);
#pragma unroll
        for (int i = 0; i < 4; ++i)
#pragma unroll
          for (int j = 0; j < 2; ++j)
            acc2[i][j] = __builtin_amdgcn_mfma_f32_16x16x32_f16(ah[i], bh[j], acc2[i][j], 0, 0, 0);
      }
    }
  }

  // epilogue: scale, stage fp16 tile into h1B (swizzled), coalesced store
  __syncthreads();  // all h1B reads done
#pragma unroll
  for (int i = 0; i < 4; ++i)
#pragma unroll
    for (int j = 0; j < 2; ++j) {
      const int nl = wc + j * 16 + r;
#pragma unroll
      for (int q = 0; q < 4; ++q) {
        const int ml = i * 16 + rq + q;
        const float v = acc2[i][j][q] * dscale[m0 + ml];
        *(unsigned short*)(h1B + ml * 256 + ((nl * 2) ^ ((ml & 7) << 4))) = f2h_bits(v);
      }
    }
  __syncthreads();
  {
    const int row = t >> 2, seg = t & 3;
    const int swz = (row & 7) << 4;
    const size_t dst = (size_t)(m0 + row) * 128 + seg * 32;
#pragma unroll
    for (int v = 0; v < 4; ++v) {
      u16x8 d = *(const u16x8*)(h1B + row * 256 + ((seg * 64 + v * 16) ^ swz));
      *(u16x8*)&td[dst + v * 8] = d;
    }
  }
}

// ---------------- tiny MLP head: 115 -> 64 -> 32 -> 1 ----------------

__global__ void k_mlp(const float* __restrict__ pooled,
                      const float* __restrict__ Wg, const float* __restrict__ bg,
                      const float* __restrict__ Wf, const float* __restrict__ bf,
                      const float* __restrict__ Wo, const float* __restrict__ bo,
                      float* __restrict__ out) {
  __shared__ float sp[F2];
  __shared__ float sg[64];
  __shared__ float sf[32];
  int g = blockIdx.x, t = threadIdx.x;
  for (int f = t; f < F2; f += 64) sp[f] = pooled[g * F2 + f];
  __syncthreads();
  float a = bg[t];
  for (int k = 0; k < F2; ++k) a += sp[k] * Wg[k * 64 + t];
  sg[t] = fmaxf(a, 0.0f);
  __syncthreads();
  if (t < 32) {
    float c = bf[t];
    for (int k = 0; k < 64; ++k) c += sg[k] * Wf[k * 32 + t];
    sf[t] = fmaxf(c, 0.0f);
  }
  __syncthreads();
  if (t == 0) {
    float c = bo[0];
    for (int k = 0; k < 32; ++k) c += sf[k] * Wo[k];
    out[g] = c;
  }
}

// ---------------- launch ----------------

extern "C" void kernel_launch(void* const* d_in, const int* in_sizes, int n_in,
                              void* d_out, int out_size, void* d_ws, size_t ws_size,
                              hipStream_t stream) {
  const float* x  = (const float*)d_in[0];
  const int* ei   = (const int*)d_in[1];
  const int* batch = (const int*)d_in[2];
  const float* W1 = (const float*)d_in[3];
  const float* b1 = (const float*)d_in[4];
  const float* W2 = (const float*)d_in[5];
  const float* b2 = (const float*)d_in[6];
  const float* Wg = (const float*)d_in[7];
  const float* bg = (const float*)d_in[8];
  const float* Wf = (const float*)d_in[9];
  const float* bf = (const float*)d_in[10];
  const float* Wo = (const float*)d_in[11];
  const float* bo = (const float*)d_in[12];
  const int* src = ei;
  const int* dst = ei + NE;

  char* p = (char*)d_ws;
  auto alloc4 = [&](size_t units) { void* r = p; p += units * 4; return r; };
  float* dinv  = (float*)alloc4(100224);
  int* cnt     = (int*)alloc4(100224);
  int* off     = (int*)alloc4(100352);
  int* cur     = (int*)alloc4(100224);
  int* bsum    = (int*)alloc4(128);
  int* srcs    = (int*)alloc4(NE);
  unsigned short* xd   = (unsigned short*)alloc4((size_t)NN * 128 / 2);    // 25.6MB
  unsigned short* aggX = (unsigned short*)alloc4((size_t)MPAD * 128 / 2);  // 25.6MB
  unsigned short* td   = (unsigned short*)alloc4((size_t)MPAD * 128 / 2);  // 25.6MB
  unsigned short* Bt1h = (unsigned short*)alloc4(256 * 128 / 2);
  unsigned short* Bt1l = (unsigned short*)alloc4(256 * 128 / 2);
  unsigned short* Bt2h = (unsigned short*)alloc4(128 * 256 / 2);
  unsigned short* Bt2l = (unsigned short*)alloc4(128 * 256 / 2);
  float* pooled = (float*)alloc4((size_t)NG * F2);

  hipMemsetAsync(cnt, 0, 100224 * sizeof(int), stream);
  hipMemsetAsync(pooled, 0, (size_t)NG * F2 * sizeof(float), stream);

  // CSR build (shared by both conv layers)
  k_count<<<(NE + 255) / 256, 256, 0, stream>>>(dst, cnt);
  k_dinv<<<(NN + 255) / 256, 256, 0, stream>>>(cnt, dinv);
  k_scan1<<<NB, SCAN_T, 0, stream>>>(cnt, off, bsum);
  k_scan2<<<1, 128, 0, stream>>>(bsum);
  k_scan3<<<(NN + 256) / 256, 256, 0, stream>>>(off, bsum, cur);
  k_place<<<(NE + 255) / 256, 256, 0, stream>>>(src, dst, cur, srcs);

  // weight prep (fp16 hi/lo, transposed, zero-padded)
  k_prepB<<<256, 128, 0, stream>>>(W1, Bt1h, Bt1l, F0, F1, 128);
  k_prepB<<<128, 256, 0, stream>>>(W2, Bt2h, Bt2l, F1, F2, 256);

  // layer 1 input: fp16 table + wave-per-node gather -> aggX fp16
  k_prepx<<<NN, 128, 0, stream>>>(x, dinv, xd);
  k_gatherw<false><<<NN / 4, 256, 0, stream>>>(xd, dinv, off, srcs,
                                               nullptr, nullptr, aggX, nullptr);

  // fused conv1-GEMM + conv2-GEMM (h1 never leaves LDS) -> td fp16
  k_fused<<<MPAD / 64, 256, 0, stream>>>(aggX, Bt1h, Bt1l, Bt2h, Bt2l,
                                         b1, dinv, td);

  // layer 2 aggregation fused with relu(+b2) + per-graph max pool
  k_gatherw<true><<<NN / 4, 256, 0, stream>>>(td, dinv, off, srcs,
                                              b2, batch, nullptr, pooled);

  // head MLP
  k_mlp<<<NG, 64, 0, stream>>>(pooled, Wg, bg, Wf, bf, Wo, bo, (float*)d_out);
}

// Round 13
// 304.122 us; speedup vs baseline: 1.1583x; 1.1088x over previous
//
#include <hip/hip_runtime.h>
#include <hip/hip_bf16.h>
#include <hip/hip_fp16.h>

#define NN 100000
#define NG 256
#define NE 800000

constexpr int F0 = 114;   // x features
constexpr int F1 = 230;   // layer1 output features
constexpr int F2 = 115;   // layer2 output features
constexpr int MPAD = 100096;  // 1564 * 64

typedef _Float16 __attribute__((ext_vector_type(8))) f16x8;   // MFMA operand
typedef __attribute__((ext_vector_type(4))) float f32x4;      // MFMA acc
typedef __attribute__((ext_vector_type(8))) unsigned short u16x8;

__device__ __forceinline__ unsigned short f2h_bits(float x) {
  _Float16 h = (_Float16)x;
  return __builtin_bit_cast(unsigned short, h);
}
__device__ __forceinline__ float h_bits2f(unsigned short u) {
  return (float)__builtin_bit_cast(_Float16, u);
}

// ---------------- degree / CSR build ----------------

__global__ void k_count(const int* __restrict__ dst, int* __restrict__ cnt) {
  int e = blockIdx.x * blockDim.x + threadIdx.x;
  if (e < NE) atomicAdd(&cnt[dst[e]], 1);
}

constexpr int SCAN_T = 256;
constexpr int SCAN_E = 1024;
constexpr int NB = (NN + SCAN_E - 1) / SCAN_E;  // 98

// scan1 also emits dinv (fused former k_dinv)
__global__ void k_scan1(const int* __restrict__ cnt, int* __restrict__ off,
                        int* __restrict__ bsum, float* __restrict__ dinv) {
  __shared__ int s[SCAN_T];
  int b = blockIdx.x, t = threadIdx.x;
  int base = b * SCAN_E + t * 4;
  int v0 = 0, v1 = 0, v2 = 0, v3 = 0;
  if (base + 0 < NN) v0 = cnt[base + 0];
  if (base + 1 < NN) v1 = cnt[base + 1];
  if (base + 2 < NN) v2 = cnt[base + 2];
  if (base + 3 < NN) v3 = cnt[base + 3];
  if (base + 0 < NN) dinv[base + 0] = rsqrtf((float)v0 + 1.0f);
  if (base + 1 < NN) dinv[base + 1] = rsqrtf((float)v1 + 1.0f);
  if (base + 2 < NN) dinv[base + 2] = rsqrtf((float)v2 + 1.0f);
  if (base + 3 < NN) dinv[base + 3] = rsqrtf((float)v3 + 1.0f);
  int sum = v0 + v1 + v2 + v3;
  s[t] = sum;
  __syncthreads();
  for (int ofs = 1; ofs < SCAN_T; ofs <<= 1) {
    int x = (t >= ofs) ? s[t - ofs] : 0;
    __syncthreads();
    s[t] += x;
    __syncthreads();
  }
  int excl = s[t] - sum;
  if (base + 0 < NN) off[base + 0] = excl;
  if (base + 1 < NN) off[base + 1] = excl + v0;
  if (base + 2 < NN) off[base + 2] = excl + v0 + v1;
  if (base + 3 < NN) off[base + 3] = excl + v0 + v1 + v2;
  if (t == SCAN_T - 1) bsum[b] = s[t];
}

// wave-parallel exclusive scan of the 98 block sums
__global__ void k_scan2(int* bsum) {
  __shared__ int ws[2];
  int t = threadIdx.x;  // 128
  int v = (t < NB) ? bsum[t] : 0;
  int orig = v;
  for (int o = 1; o < 64; o <<= 1) {
    int x = __shfl_up(v, o, 64);
    if ((t & 63) >= o) v += x;
  }
  if ((t & 63) == 63) ws[t >> 6] = v;
  __syncthreads();
  if (t >= 64) v += ws[0];
  if (t < NB) bsum[t] = v - orig;
}

__global__ void k_scan3(int* __restrict__ off, const int* __restrict__ bsum,
                        int* __restrict__ cur) {
  int i = blockIdx.x * blockDim.x + threadIdx.x;
  if (i < NN) {
    int v = off[i] + bsum[i / SCAN_E];
    off[i] = v;
    cur[i] = v;
  }
  if (i == NN) off[NN] = NE;
}

__global__ void k_place(const int* __restrict__ src, const int* __restrict__ dst,
                        int* __restrict__ cur, int* __restrict__ srcs) {
  int e = blockIdx.x * blockDim.x + threadIdx.x;
  if (e >= NE) return;
  int p = atomicAdd(&cur[dst[e]], 1);
  srcs[p] = src[e];
}

// ---------------- fp16 tables ----------------

__global__ void k_prepx(const float* __restrict__ x, const float* __restrict__ dinv,
                        unsigned short* __restrict__ xd) {
  int n = blockIdx.x, f = threadIdx.x;  // 128 threads
  float v = (f < F0) ? x[(size_t)n * F0 + f] * dinv[n] : 0.0f;
  xd[(size_t)n * 128 + f] = f2h_bits(v);
}

// ---------------- wave-per-node gather: 16 edge slots/iter, 4 loads in flight

template <bool POOL>
__global__ __launch_bounds__(256) void k_gatherw(
    const unsigned short* __restrict__ tab, const float* __restrict__ dinv,
    const int* __restrict__ off, const int* __restrict__ srcs,
    const float* __restrict__ b2, const int* __restrict__ batch,
    unsigned short* __restrict__ outh, float* __restrict__ pooled) {
  __shared__ float smax[4][128];
  __shared__ int sg[4];
  int w = threadIdx.x >> 6, lane = threadIdx.x & 63;
  int n = blockIdx.x * 4 + w;
  int grp = lane >> 4, sub = lane & 15;
  int fb = sub * 8;

  float acc[8] = {0.f, 0.f, 0.f, 0.f, 0.f, 0.f, 0.f, 0.f};
  int j0 = off[n], j1 = off[n + 1];  // slots j0..j1, self at j1
  for (int base = j0; base <= j1; base += 16) {
    int row[4];
    u16x8 v[4];
    bool has[4];
#pragma unroll
    for (int c = 0; c < 4; ++c) {
      int je = base + c * 4 + grp;
      row[c] = (je < j1) ? srcs[je] : ((je == j1) ? n : -1);
      has[c] = row[c] >= 0;
    }
#pragma unroll
    for (int c = 0; c < 4; ++c)
      if (has[c]) v[c] = *(const u16x8*)&tab[(size_t)row[c] * 128 + fb];
#pragma unroll
    for (int c = 0; c < 4; ++c)
      if (has[c]) {
#pragma unroll
        for (int u = 0; u < 8; ++u) acc[u] += h_bits2f(v[c][u]);
      }
  }
#pragma unroll
  for (int u = 0; u < 8; ++u) {
    acc[u] += __shfl_xor(acc[u], 16);
    acc[u] += __shfl_xor(acc[u], 32);
  }
  float dn = dinv[n];

  if constexpr (!POOL) {
    if (grp == 0) {
      u16x8 o;
#pragma unroll
      for (int u = 0; u < 8; ++u) o[u] = f2h_bits(acc[u] * dn);
      *(u16x8*)&outh[(size_t)n * 128 + fb] = o;
    }
  } else {
    if (grp == 0) {
#pragma unroll
      for (int u = 0; u < 8; ++u) {
        int f = fb + u;
        float bb = (f < F2) ? b2[f] : 0.0f;
        smax[w][f] = fmaxf(acc[u] * dn + bb, 0.0f);
      }
      if (sub == 0) sg[w] = batch[n];
    }
    __syncthreads();
    int t = threadIdx.x;
    if (t < 128) {
      int g0 = sg[0];
      bool same = (sg[1] == g0) & (sg[2] == g0) & (sg[3] == g0);
      if (same) {
        float m = fmaxf(fmaxf(smax[0][t], smax[1][t]),
                        fmaxf(smax[2][t], smax[3][t]));
        if (t < F2 && m > 0.0f)
          atomicMax((int*)&pooled[g0 * F2 + t], __float_as_int(m));
      } else {
        for (int ww = 0; ww < 4; ++ww) {
          float m = smax[ww][t];
          if (t < F2 && m > 0.0f)
            atomicMax((int*)&pooled[sg[ww] * F2 + t], __float_as_int(m));
        }
      }
    }
  }
}

// ---------------- weight split+transpose prep (both matrices, one launch) ----

__global__ void k_prepB2(const float* __restrict__ W1, const float* __restrict__ W2,
                         unsigned short* __restrict__ B1h, unsigned short* __restrict__ B1l,
                         unsigned short* __restrict__ B2h, unsigned short* __restrict__ B2l) {
  int b = blockIdx.x, t = threadIdx.x;  // 256 threads
  if (b < 128) {  // B1: [256 n][128 k], two n-rows per block
    int n = b * 2 + (t >> 7), k = t & 127;
    float v = (k < F0 && n < F1) ? W1[(size_t)k * F1 + n] : 0.0f;
    unsigned short h = f2h_bits(v);
    unsigned short l = f2h_bits(v - h_bits2f(h));
    B1h[(size_t)n * 128 + k] = h;
    B1l[(size_t)n * 128 + k] = l;
  } else {        // B2: [128 n][256 k]
    int n = b - 128, k = t;
    float v = (k < F1 && n < F2) ? W2[(size_t)k * F2 + n] : 0.0f;
    unsigned short h = f2h_bits(v);
    unsigned short l = f2h_bits(v - h_bits2f(h));
    B2h[(size_t)n * 256 + k] = h;
    B2l[(size_t)n * 256 + k] = l;
  }
}

// ---------------- fused double GEMM v4: td = (relu(aggX@W1t^T+b1) @ W2t^T)*dinv
// Round-10 structure (As/Bs staged per round, only accumulators live across
// barriers) + compact XOR-swizzled LDS: h1 64x512B + As 64x128B + Bs 2x128x128B
// = 72 KB -> 2 blocks/CU. Swizzle: byte ^= (row&7)<<4 (verified v3/r11-12).

__global__ __launch_bounds__(256) void k_fused(
    const unsigned short* __restrict__ A,                                   // [MPAD][128]
    const unsigned short* __restrict__ B1h, const unsigned short* __restrict__ B1l,  // [256][128]
    const unsigned short* __restrict__ B2h, const unsigned short* __restrict__ B2l,  // [128][256]
    const float* __restrict__ b1, const float* __restrict__ dscale,
    unsigned short* __restrict__ td) {                                      // [MPAD][128]
  __shared__ char lds[73728];
  char* h1B = lds;            // 32768 B: 64 rows x 512 B (256 fp16 cols, swizzled)
  char* AsB = lds + 32768;    //  8192 B: 64 rows x 128 B (64 fp16 k, swizzled)
  char* Bs0 = lds + 40960;    // 16384 B: 128 rows x 128 B (hi)
  char* Bs1 = lds + 57344;    // (lo)

  const int t = threadIdx.x;
  const int m0 = blockIdx.x * 64;
  const int lane = t & 63, w = t >> 6;
  const int r = lane & 15;
  const int kq = lane >> 4;          // k-quarter 0..3
  const int kb16 = kq * 16;          // byte offset of lane's 16B k-frag in 128B
  const int rq = kq * 4;
  const int wc = w * 32;             // wave's 32-col slice
  const int swr = (r & 7) << 4;      // MFMA-read swizzle (row&7 == r&7 everywhere)
  const int arow = t >> 2, aq = t & 3, aswz = (arow & 7) << 4;
  const int brow = t >> 1, bseg = t & 1, bswz = (brow & 7) << 4;

  f32x4 acc2[4][2];
#pragma unroll
  for (int i = 0; i < 4; ++i)
#pragma unroll
    for (int j = 0; j < 2; ++j) acc2[i][j] = (f32x4){0.f, 0.f, 0.f, 0.f};

  // ---------- stage 1: h1B = fp16(relu(aggX @ W1t^T + b1)), full 256 cols ----
  for (int h = 0; h < 2; ++h) {
    f32x4 acc[4][2];
#pragma unroll
    for (int i = 0; i < 4; ++i)
#pragma unroll
      for (int j = 0; j < 2; ++j) acc[i][j] = (f32x4){0.f, 0.f, 0.f, 0.f};

    for (int kc = 0; kc < 2; ++kc) {
      __syncthreads();  // As/Bs free (previous consumers done)
      {
        size_t ga = (size_t)(m0 + arow) * 128 + kc * 64 + aq * 16;
        *(u16x8*)(AsB + arow * 128 + ((aq * 32) ^ aswz))      = *(const u16x8*)&A[ga];
        *(u16x8*)(AsB + arow * 128 + ((aq * 32 + 16) ^ aswz)) = *(const u16x8*)&A[ga + 8];
        size_t gb = (size_t)(h * 128 + brow) * 128 + kc * 64 + bseg * 32;
#pragma unroll
        for (int v = 0; v < 4; ++v) {
          const int bo = (bseg * 64 + v * 16) ^ bswz;
          *(u16x8*)(Bs0 + brow * 128 + bo) = *(const u16x8*)&B1h[gb + v * 8];
          *(u16x8*)(Bs1 + brow * 128 + bo) = *(const u16x8*)&B1l[gb + v * 8];
        }
      }
      __syncthreads();
#pragma unroll
      for (int ks = 0; ks < 2; ++ks) {
        f16x8 av[4], bh[2], bl[2];
#pragma unroll
        for (int i = 0; i < 4; ++i)
          av[i] = *(const f16x8*)(AsB + (i * 16 + r) * 128 + ((ks * 64 + kb16) ^ swr));
#pragma unroll
        for (int j = 0; j < 2; ++j) {
          const int row = wc + j * 16 + r;
          const int bo = (ks * 64 + kb16) ^ swr;
          bh[j] = *(const f16x8*)(Bs0 + row * 128 + bo);
          bl[j] = *(const f16x8*)(Bs1 + row * 128 + bo);
        }
#pragma unroll
        for (int i = 0; i < 4; ++i)
#pragma unroll
          for (int j = 0; j < 2; ++j)
            acc[i][j] = __builtin_amdgcn_mfma_f32_16x16x32_f16(av[i], bl[j], acc[i][j], 0, 0, 0);
#pragma unroll
        for (int i = 0; i < 4; ++i)
#pragma unroll
          for (int j = 0; j < 2; ++j)
            acc[i][j] = __builtin_amdgcn_mfma_f32_16x16x32_f16(av[i], bh[j], acc[i][j], 0, 0, 0);
      }
    }

    // bias+relu -> h1B (swizzled; h halves write disjoint byte ranges)
    // C/D layout: col = lane&15 (n), row = kq*4 + q (m)  [m89/m91]
#pragma unroll
    for (int i = 0; i < 4; ++i)
#pragma unroll
      for (int j = 0; j < 2; ++j) {
        const int nl = wc + j * 16 + r;
        const int n = h * 128 + nl;
        const bool val = n < F1;
        const float bb = val ? b1[n] : 0.0f;
#pragma unroll
        for (int q = 0; q < 4; ++q) {
          const int ml = i * 16 + rq + q;
          const float v = val ? fmaxf(acc[i][j][q] + bb, 0.0f) : 0.0f;
          *(unsigned short*)(h1B + ml * 512 + ((n * 2) ^ ((ml & 7) << 4))) = f2h_bits(v);
        }
      }
  }

  // ---------- stage 2: acc2 = (h1B @ W2t^T), K = 256 ----------
  for (int kc = 0; kc < 4; ++kc) {
    __syncthreads();  // kc=0 also fences h1B writes
    {
      size_t gb = (size_t)brow * 256 + kc * 64 + bseg * 32;
#pragma unroll
      for (int v = 0; v < 4; ++v) {
        const int bo = (bseg * 64 + v * 16) ^ bswz;
        *(u16x8*)(Bs0 + brow * 128 + bo) = *(const u16x8*)&B2h[gb + v * 8];
        *(u16x8*)(Bs1 + brow * 128 + bo) = *(const u16x8*)&B2l[gb + v * 8];
      }
    }
    __syncthreads();
#pragma unroll
    for (int ks = 0; ks < 2; ++ks) {
      f16x8 ah[4], bh[2], bl[2];
#pragma unroll
      for (int i = 0; i < 4; ++i) {
        const int row = i * 16 + r;
        ah[i] = *(const f16x8*)(h1B + row * 512 + ((kc * 128 + ks * 64 + kb16) ^ swr));
      }
#pragma unroll
      for (int j = 0; j < 2; ++j) {
        const int row = wc + j * 16 + r;
        const int bo = (ks * 64 + kb16) ^ swr;
        bh[j] = *(const f16x8*)(Bs0 + row * 128 + bo);
        bl[j] = *(const f16x8*)(Bs1 + row * 128 + bo);
      }
#pragma unroll
      for (int i = 0; i < 4; ++i)
#pragma unroll
        for (int j = 0; j < 2; ++j)
          acc2[i][j] = __builtin_amdgcn_mfma_f32_16x16x32_f16(ah[i], bl[j], acc2[i][j], 0, 0, 0);
#pragma unroll
      for (int i = 0; i < 4; ++i)
#pragma unroll
        for (int j = 0; j < 2; ++j)
          acc2[i][j] = __builtin_amdgcn_mfma_f32_16x16x32_f16(ah[i], bh[j], acc2[i][j], 0, 0, 0);
    }
  }

  // epilogue: scale, stage fp16 tile into h1B (swizzled), coalesced store
  __syncthreads();  // all h1B reads done
#pragma unroll
  for (int i = 0; i < 4; ++i)
#pragma unroll
    for (int j = 0; j < 2; ++j) {
      const int nl = wc + j * 16 + r;
#pragma unroll
      for (int q = 0; q < 4; ++q) {
        const int ml = i * 16 + rq + q;
        const float v = acc2[i][j][q] * dscale[m0 + ml];
        *(unsigned short*)(h1B + ml * 512 + ((nl * 2) ^ ((ml & 7) << 4))) = f2h_bits(v);
      }
    }
  __syncthreads();
  {
    const int row = t >> 2, seg = t & 3;
    const int swz = (row & 7) << 4;
    const size_t dst = (size_t)(m0 + row) * 128 + seg * 32;
#pragma unroll
    for (int v = 0; v < 4; ++v) {
      u16x8 d = *(const u16x8*)(h1B + row * 512 + ((seg * 64 + v * 16) ^ swz));
      *(u16x8*)&td[dst + v * 8] = d;
    }
  }
}

// ---------------- tiny MLP head: 115 -> 64 -> 32 -> 1 ----------------

__global__ void k_mlp(const float* __restrict__ pooled,
                      const float* __restrict__ Wg, const float* __restrict__ bg,
                      const float* __restrict__ Wf, const float* __restrict__ bf,
                      const float* __restrict__ Wo, const float* __restrict__ bo,
                      float* __restrict__ out) {
  __shared__ float sp[F2];
  __shared__ float sg[64];
  __shared__ float sf[32];
  int g = blockIdx.x, t = threadIdx.x;
  for (int f = t; f < F2; f += 64) sp[f] = pooled[g * F2 + f];
  __syncthreads();
  float a = bg[t];
  for (int k = 0; k < F2; ++k) a += sp[k] * Wg[k * 64 + t];
  sg[t] = fmaxf(a, 0.0f);
  __syncthreads();
  if (t < 32) {
    float c = bf[t];
    for (int k = 0; k < 64; ++k) c += sg[k] * Wf[k * 32 + t];
    sf[t] = fmaxf(c, 0.0f);
  }
  __syncthreads();
  if (t == 0) {
    float c = bo[0];
    for (int k = 0; k < 32; ++k) c += sf[k] * Wo[k];
    out[g] = c;
  }
}

// ---------------- launch ----------------

extern "C" void kernel_launch(void* const* d_in, const int* in_sizes, int n_in,
                              void* d_out, int out_size, void* d_ws, size_t ws_size,
                              hipStream_t stream) {
  const float* x  = (const float*)d_in[0];
  const int* ei   = (const int*)d_in[1];
  const int* batch = (const int*)d_in[2];
  const float* W1 = (const float*)d_in[3];
  const float* b1 = (const float*)d_in[4];
  const float* W2 = (const float*)d_in[5];
  const float* b2 = (const float*)d_in[6];
  const float* Wg = (const float*)d_in[7];
  const float* bg = (const float*)d_in[8];
  const float* Wf = (const float*)d_in[9];
  const float* bf = (const float*)d_in[10];
  const float* Wo = (const float*)d_in[11];
  const float* bo = (const float*)d_in[12];
  const int* src = ei;
  const int* dst = ei + NE;

  char* p = (char*)d_ws;
  auto alloc4 = [&](size_t units) { void* r = p; p += units * 4; return r; };
  float* dinv  = (float*)alloc4(100224);
  int* cnt     = (int*)alloc4(100224);
  int* off     = (int*)alloc4(100352);
  int* cur     = (int*)alloc4(100224);
  int* bsum    = (int*)alloc4(128);
  int* srcs    = (int*)alloc4(NE);
  unsigned short* xd   = (unsigned short*)alloc4((size_t)NN * 128 / 2);    // 25.6MB
  unsigned short* aggX = (unsigned short*)alloc4((size_t)MPAD * 128 / 2);  // 25.6MB
  unsigned short* td   = (unsigned short*)alloc4((size_t)MPAD * 128 / 2);  // 25.6MB
  unsigned short* Bt1h = (unsigned short*)alloc4(256 * 128 / 2);
  unsigned short* Bt1l = (unsigned short*)alloc4(256 * 128 / 2);
  unsigned short* Bt2h = (unsigned short*)alloc4(128 * 256 / 2);
  unsigned short* Bt2l = (unsigned short*)alloc4(128 * 256 / 2);
  float* pooled = (float*)alloc4((size_t)NG * F2);

  hipMemsetAsync(cnt, 0, 100224 * sizeof(int), stream);
  hipMemsetAsync(pooled, 0, (size_t)NG * F2 * sizeof(float), stream);

  // CSR build (shared by both conv layers); scan1 also emits dinv
  k_count<<<(NE + 255) / 256, 256, 0, stream>>>(dst, cnt);
  k_scan1<<<NB, SCAN_T, 0, stream>>>(cnt, off, bsum, dinv);
  k_scan2<<<1, 128, 0, stream>>>(bsum);
  k_scan3<<<(NN + 256) / 256, 256, 0, stream>>>(off, bsum, cur);
  k_place<<<(NE + 255) / 256, 256, 0, stream>>>(src, dst, cur, srcs);

  // weight prep (fp16 hi/lo, transposed, zero-padded) — single launch
  k_prepB2<<<256, 256, 0, stream>>>(W1, W2, Bt1h, Bt1l, Bt2h, Bt2l);

  // layer 1 input: fp16 table + wave-per-node gather -> aggX fp16
  k_prepx<<<NN, 128, 0, stream>>>(x, dinv, xd);
  k_gatherw<false><<<NN / 4, 256, 0, stream>>>(xd, dinv, off, srcs,
                                               nullptr, nullptr, aggX, nullptr);

  // fused conv1-GEMM + conv2-GEMM (h1 never leaves LDS) -> td fp16
  k_fused<<<MPAD / 64, 256, 0, stream>>>(aggX, Bt1h, Bt1l, Bt2h, Bt2l,
                                         b1, dinv, td);

  // layer 2 aggregation fused with relu(+b2) + per-graph max pool
  k_gatherw<true><<<NN / 4, 256, 0, stream>>>(td, dinv, off, srcs,
                                              b2, batch, nullptr, pooled);

  // head MLP
  k_mlp<<<NG, 64, 0, stream>>>(pooled, Wg, bg, Wf, bf, Wo, bo, (float*)d_out);
}